// Round 12
// baseline (259.295 us; speedup 1.0000x reference)
//
#include <hip/hip_runtime.h>
#include <hip/hip_cooperative_groups.h>

namespace cg = cooperative_groups;

// SAGEConv-mean: out[n,:] = (sum_{e: dst[e]==n} x[src[e],:]) / deg[n] @ W^T + b
// N=100000, E=1000000, D=64, fp32 in/out (no fp32 MFMA -> VALU GEMM).
//
// Round 12: intra-kernel tweaks plateaued (gather ~LLC random-BW floor). Attack
// dispatch structure: ONE cooperative persistent kernel (512 blocks x 512 thr,
// 34.8KB LDS union -> 2 blocks/CU guaranteed co-resident under lb(512,4)):
//   phase1 zero cursors -> grid.sync -> phase2 grid-stride {partition | xw 64-node
//   tiles} -> grid.sync -> phase3 grid-stride gather buckets.
// Kills the 8KB memset dispatch + 2 inter-dispatch gaps + tail-drain serialization.
// If hipLaunchCooperativeKernel errors -> r10's proven 3-dispatch chain (same call).
// Fallback C: atomic scatter + LDS GEMM (ws too small or N >= 2^17 or nb > MAXB).

#define D 64
#define BSHIFT 7                  // 128 nodes per bucket
#define BNODES (1 << BSHIFT)
#define CAP 2048                  // static slots per bucket (mean fill 1280)
#define GTHREADS 512
#define PERTHREAD (CAP / GTHREADS)   // 4
#define PXW_THREADS 512
#define MAXB 2048
#define COOP_GRID 512

__device__ inline int detect_stride_block(const unsigned* __restrict__ words,
                                          int E, int* sflag) {
    int t = threadIdx.x;
    if (t < 64) {
        unsigned v = (t < E) ? words[2 * t + 1] : 0u;
        int any = __any(v != 0u);
        if (t == 0) *sflag = any ? 1 : 2;   // word stride: 1=int32, 2=int64
    }
    __syncthreads();
    return *sflag;
}

__device__ inline unsigned pack_bf16(float a, float b) {   // two fp32 -> bf16x2, RNE
    unsigned ua = __float_as_uint(a), ub = __float_as_uint(b);
    ua += 0x7fffu + ((ua >> 16) & 1u);
    ub += 0x7fffu + ((ub >> 16) & 1u);
    return (ua >> 16) | (ub & 0xffff0000u);
}

// ==================== cooperative fused kernel ====================
__global__ __launch_bounds__(512, 4) void fused_all(
        const unsigned* __restrict__ ewords, int* __restrict__ cursor,
        unsigned* __restrict__ pairs, uint2* __restrict__ spill,
        int* __restrict__ spillCnt,
        const float* __restrict__ x, const float* __restrict__ W,
        unsigned* __restrict__ y2,
        const float* __restrict__ deg, const float* __restrict__ bias,
        float* __restrict__ out,
        int E, int N, int nb, int pblocks, int xwblocks) {
    __shared__ __align__(16) char smem[34832];
    int t = threadIdx.x;
    cg::grid_group grid = cg::this_grid();

    // ---- phase 1: zero cursors + spillCnt (cursor[MAXB] then spillCnt) ----
    for (int i = blockIdx.x * 512 + t; i < MAXB + 16; i += gridDim.x * 512)
        cursor[i] = 0;
    grid.sync();

    // ---- phase 2: partition (vb < pblocks) | xw 64-node tile (rest) ----
    for (int vb = blockIdx.x; vb < pblocks + xwblocks; vb += gridDim.x) {
        __syncthreads();                          // smem reuse across vbs
        if (vb < pblocks) {
            int* lhist = (int*)smem;
            int* lbase = lhist + MAXB;
            int* sflag = lbase + MAXB;
            int s = detect_stride_block(ewords, E, sflag);
            int base = vb * 8192;
            for (int i = t; i < nb; i += 512) lhist[i] = 0;
            __syncthreads();
            unsigned pv[16]; int bk[16];
            #pragma unroll
            for (int k = 0; k < 16; ++k) {
                int e = base + k * 512 + t;
                bk[k] = -1;
                if (e < E) {
                    unsigned src = ewords[(size_t)e * s];
                    unsigned dst = ewords[((size_t)E + e) * s];
                    bk[k] = (int)(dst >> BSHIFT);
                    pv[k] = src | ((dst & (BNODES - 1)) << 17);
                    atomicAdd(&lhist[bk[k]], 1);
                }
            }
            __syncthreads();
            for (int hb = t; hb < nb; hb += 512) {
                int cc = lhist[hb];
                if (cc) lbase[hb] = atomicAdd(&cursor[hb], cc);
                lhist[hb] = 0;                    // reuse as running cursor
            }
            __syncthreads();
            #pragma unroll
            for (int k = 0; k < 16; ++k) {
                if (bk[k] >= 0) {
                    int lpos = lbase[bk[k]] + atomicAdd(&lhist[bk[k]], 1);
                    if (lpos < CAP) {
                        pairs[(size_t)bk[k] * CAP + lpos] = pv[k];
                    } else {                      // overflow (never for this input)
                        int si = atomicAdd(spillCnt, 1);
                        unsigned dst = ((unsigned)bk[k] << BSHIFT) | (pv[k] >> 17);
                        spill[si] = make_uint2(pv[k] & 0x1FFFFu, dst);
                    }
                }
            }
        } else {
            // xw: 64-node tile, 2x4 outputs/thread
            float* Wt = (float*)smem;             // Wt[k*68+o], 17408B
            float* xs = Wt + 64 * 68;             // xs[nl*68+k], 17408B
            for (int i = t; i < 64 * 64; i += 512) {
                int o = i >> 6, k = i & 63;
                Wt[k * 68 + o] = W[i];
            }
            int base = (vb - pblocks) * 64;
            int idx = t;
            #pragma unroll
            for (int r = 0; r < 2; ++r, idx += 512) {   // stage 64 rows
                int nl = idx >> 4, c4 = (idx & 15) * 4;
                int n = base + nl;
                float4 v = {0.f, 0.f, 0.f, 0.f};
                if (n < N) v = *(const float4*)(x + (size_t)n * 64 + c4);
                *(float4*)&xs[nl * 68 + c4] = v;
            }
            __syncthreads();
            int o4 = (t & 15) * 4, nl2 = (t >> 4) * 2;
            float acc[2][4];
            #pragma unroll
            for (int i = 0; i < 2; ++i)
                #pragma unroll
                for (int j = 0; j < 4; ++j) acc[i][j] = 0.f;
            #pragma unroll 2
            for (int k0 = 0; k0 < 64; k0 += 4) {
                float a[2][4], wv[4][4];
                #pragma unroll
                for (int i = 0; i < 2; ++i)
                    *(float4*)a[i] = *(const float4*)&xs[(nl2 + i) * 68 + k0];
                #pragma unroll
                for (int dk = 0; dk < 4; ++dk)
                    *(float4*)wv[dk] = *(const float4*)&Wt[(k0 + dk) * 68 + o4];
                #pragma unroll
                for (int i = 0; i < 2; ++i)
                    #pragma unroll
                    for (int j = 0; j < 4; ++j)
                        acc[i][j] += a[i][0] * wv[0][j] + a[i][1] * wv[1][j]
                                   + a[i][2] * wv[2][j] + a[i][3] * wv[3][j];
            }
            int n0 = base + nl2;
            #pragma unroll
            for (int i = 0; i < 2; ++i) {
                if (n0 + i < N) {
                    uint2 p;
                    p.x = pack_bf16(acc[i][0], acc[i][1]);
                    p.y = pack_bf16(acc[i][2], acc[i][3]);
                    *(uint2*)(y2 + (size_t)(n0 + i) * 32 + (o4 >> 1)) = p;
                }
            }
        }
    }
    grid.sync();

    // ---- phase 3: gather buckets ----
    int lane = t & 63, w = t >> 6;
    int g = lane >> 4, c = lane & 15;
    float4 bv = ((const float4*)bias)[c];
    unsigned* list = (unsigned*)smem;             // 8192B
    int* cnt = (int*)(smem + 8192);
    int* st  = cnt + BNODES;
    int* sc  = st + BNODES;
    for (int bkt = blockIdx.x; bkt < nb; bkt += gridDim.x) {
        __syncthreads();                          // smem reuse across buckets
        int base = bkt << BSHIFT;
        int total = cursor[bkt];
        int cn = total < CAP ? total : CAP;
        if (t < BNODES) cnt[t] = 0;
        __syncthreads();
        unsigned pv[PERTHREAD];
        #pragma unroll
        for (int j = 0; j < PERTHREAD; ++j) {
            int i = t + j * GTHREADS;
            pv[j] = (i < cn) ? pairs[(size_t)bkt * CAP + i] : 0xFFFFFFFFu;
            if (i < cn) atomicAdd(&cnt[pv[j] >> 17], 1);
        }
        __syncthreads();
        if (t < BNODES) sc[t] = cnt[t];
        __syncthreads();
        for (int off = 1; off < BNODES; off <<= 1) {
            int v = (t < BNODES && t >= off) ? sc[t - off] : 0;
            __syncthreads();
            if (t < BNODES) sc[t] += v;
            __syncthreads();
        }
        if (t < BNODES) { st[t] = sc[t] - cnt[t]; sc[t] = sc[t] - cnt[t]; }
        __syncthreads();
        #pragma unroll
        for (int j = 0; j < PERTHREAD; ++j) {
            if (pv[j] != 0xFFFFFFFFu) {
                int pos = atomicAdd(&sc[pv[j] >> 17], 1);
                list[pos] = pv[j] & 0x1FFFFu;
            }
        }
        __syncthreads();
        int scnt = *spillCnt;                     // 0 in practice
        for (int nl0 = w * 16; nl0 < w * 16 + 16; nl0 += 4) {
            int mynode = nl0 + g;
            int n = base + mynode;
            int s0 = st[mynode], e1 = s0 + cnt[mynode];
            float ax = 0.f, ay = 0.f, az = 0.f, aw = 0.f;
            float bx = 0.f, by = 0.f, bz = 0.f, bw = 0.f;
            int i = s0;
            for (; i + 1 < e1; i += 2) {
                unsigned s0v = list[i], s1v = list[i + 1];
                uint2 u0 = *(const uint2*)(y2 + (size_t)s0v * 32 + c * 2);
                uint2 u1 = *(const uint2*)(y2 + (size_t)s1v * 32 + c * 2);
                ax += __uint_as_float(u0.x << 16);
                ay += __uint_as_float(u0.x & 0xffff0000u);
                az += __uint_as_float(u0.y << 16);
                aw += __uint_as_float(u0.y & 0xffff0000u);
                bx += __uint_as_float(u1.x << 16);
                by += __uint_as_float(u1.x & 0xffff0000u);
                bz += __uint_as_float(u1.y << 16);
                bw += __uint_as_float(u1.y & 0xffff0000u);
            }
            if (i < e1) {
                unsigned sv = list[i];
                uint2 u = *(const uint2*)(y2 + (size_t)sv * 32 + c * 2);
                ax += __uint_as_float(u.x << 16);
                ay += __uint_as_float(u.x & 0xffff0000u);
                az += __uint_as_float(u.y << 16);
                aw += __uint_as_float(u.y & 0xffff0000u);
            }
            ax += bx; ay += by; az += bz; aw += bw;
            for (int k = 0; k < scnt; ++k) {      // overflow path (empty)
                uint2 e = spill[k];
                if ((int)e.y == n) {
                    uint2 u = *(const uint2*)(y2 + (size_t)e.x * 32 + c * 2);
                    ax += __uint_as_float(u.x << 16);
                    ay += __uint_as_float(u.x & 0xffff0000u);
                    az += __uint_as_float(u.y << 16);
                    aw += __uint_as_float(u.y & 0xffff0000u);
                }
            }
            if (n < N) {
                float invd = 1.0f / deg[n];
                float4 o4 = {ax * invd + bv.x, ay * invd + bv.y,
                             az * invd + bv.z, aw * invd + bv.w};
                *(float4*)(out + (size_t)n * 64 + c * 4) = o4;
            }
        }
    }
}

// ==================== r10 3-dispatch fallback ====================
__global__ __launch_bounds__(PXW_THREADS, 4) void partition_xw_kernel(
        const unsigned* __restrict__ ewords, int* __restrict__ cursor,
        unsigned* __restrict__ pairs, uint2* __restrict__ spill,
        int* __restrict__ spillCnt,
        const float* __restrict__ x, const float* __restrict__ W,
        unsigned* __restrict__ y2, int E, int N, int nb, int pblocks) {
    __shared__ __align__(16) char smem[52240];
    int t = threadIdx.x;
    if ((int)blockIdx.x < pblocks) {
        int* lhist = (int*)smem;
        int* lbase = lhist + MAXB;
        int* sflag = lbase + MAXB;
        int s = detect_stride_block(ewords, E, sflag);
        int base = blockIdx.x * 8192;
        for (int i = t; i < nb; i += PXW_THREADS) lhist[i] = 0;
        __syncthreads();
        unsigned pv[16]; int bk[16];
        #pragma unroll
        for (int k = 0; k < 16; ++k) {
            int e = base + k * PXW_THREADS + t;
            bk[k] = -1;
            if (e < E) {
                unsigned src = ewords[(size_t)e * s];
                unsigned dst = ewords[((size_t)E + e) * s];
                bk[k] = (int)(dst >> BSHIFT);
                pv[k] = src | ((dst & (BNODES - 1)) << 17);
                atomicAdd(&lhist[bk[k]], 1);
            }
        }
        __syncthreads();
        for (int hb = t; hb < nb; hb += PXW_THREADS) {
            int cc = lhist[hb];
            if (cc) lbase[hb] = atomicAdd(&cursor[hb], cc);
            lhist[hb] = 0;
        }
        __syncthreads();
        #pragma unroll
        for (int k = 0; k < 16; ++k) {
            if (bk[k] >= 0) {
                int lpos = lbase[bk[k]] + atomicAdd(&lhist[bk[k]], 1);
                if (lpos < CAP) {
                    pairs[(size_t)bk[k] * CAP + lpos] = pv[k];
                } else {
                    int si = atomicAdd(spillCnt, 1);
                    unsigned dst = ((unsigned)bk[k] << BSHIFT) | (pv[k] >> 17);
                    spill[si] = make_uint2(pv[k] & 0x1FFFFu, dst);
                }
            }
        }
    } else {
        float* Wt = (float*)smem;
        float* xs = Wt + 64 * 68;
        for (int i = t; i < 64 * 64; i += PXW_THREADS) {
            int o = i >> 6, k = i & 63;
            Wt[k * 68 + o] = W[i];
        }
        int base = ((int)blockIdx.x - pblocks) * 128;
        int row = t >> 4, c4 = (t & 15) * 4;
        #pragma unroll
        for (int r = 0; r < 4; ++r) {
            int nl = row + r * 32;
            int n = base + nl;
            float4 v = {0.f, 0.f, 0.f, 0.f};
            if (n < N) v = *(const float4*)(x + (size_t)n * 64 + c4);
            *(float4*)&xs[nl * 68 + c4] = v;
        }
        __syncthreads();
        int o4 = (t & 15) * 4, nl4 = (t >> 4) * 4;
        float acc[4][4];
        #pragma unroll
        for (int i = 0; i < 4; ++i)
            #pragma unroll
            for (int j = 0; j < 4; ++j) acc[i][j] = 0.f;
        #pragma unroll 2
        for (int k0 = 0; k0 < 64; k0 += 4) {
            float a[4][4], wv[4][4];
            #pragma unroll
            for (int i = 0; i < 4; ++i)
                *(float4*)a[i] = *(const float4*)&xs[(nl4 + i) * 68 + k0];
            #pragma unroll
            for (int dk = 0; dk < 4; ++dk)
                *(float4*)wv[dk] = *(const float4*)&Wt[(k0 + dk) * 68 + o4];
            #pragma unroll
            for (int i = 0; i < 4; ++i)
                #pragma unroll
                for (int j = 0; j < 4; ++j)
                    acc[i][j] += a[i][0] * wv[0][j] + a[i][1] * wv[1][j]
                               + a[i][2] * wv[2][j] + a[i][3] * wv[3][j];
        }
        int n0 = base + nl4;
        #pragma unroll
        for (int i = 0; i < 4; ++i) {
            if (n0 + i < N) {
                uint2 p;
                p.x = pack_bf16(acc[i][0], acc[i][1]);
                p.y = pack_bf16(acc[i][2], acc[i][3]);
                *(uint2*)(y2 + (size_t)(n0 + i) * 32 + (o4 >> 1)) = p;
            }
        }
    }
}

__global__ __launch_bounds__(GTHREADS) void bucket_gather(
        const unsigned* __restrict__ y2, const unsigned* __restrict__ pairs,
        const int* __restrict__ cursor, const uint2* __restrict__ spill,
        const int* __restrict__ spillCnt,
        const float* __restrict__ deg, const float* __restrict__ b,
        float* __restrict__ out, int N) {
    __shared__ unsigned list[CAP];
    __shared__ int cnt[BNODES], st[BNODES], sc[BNODES];
    int t = threadIdx.x;
    int bkt = blockIdx.x, base = bkt << BSHIFT;
    int total = cursor[bkt];
    int cn = total < CAP ? total : CAP;
    int lane = t & 63, w = t >> 6;
    int g = lane >> 4, c = lane & 15;
    float4 bv = ((const float4*)b)[c];

    if (t < BNODES) cnt[t] = 0;
    __syncthreads();
    unsigned pv[PERTHREAD];
    #pragma unroll
    for (int j = 0; j < PERTHREAD; ++j) {
        int i = t + j * GTHREADS;
        pv[j] = (i < cn) ? pairs[(size_t)bkt * CAP + i] : 0xFFFFFFFFu;
        if (i < cn) atomicAdd(&cnt[pv[j] >> 17], 1);
    }
    __syncthreads();
    if (t < BNODES) sc[t] = cnt[t];
    __syncthreads();
    for (int off = 1; off < BNODES; off <<= 1) {
        int v = (t < BNODES && t >= off) ? sc[t - off] : 0;
        __syncthreads();
        if (t < BNODES) sc[t] += v;
        __syncthreads();
    }
    if (t < BNODES) { st[t] = sc[t] - cnt[t]; sc[t] = sc[t] - cnt[t]; }
    __syncthreads();
    #pragma unroll
    for (int j = 0; j < PERTHREAD; ++j) {
        if (pv[j] != 0xFFFFFFFFu) {
            int pos = atomicAdd(&sc[pv[j] >> 17], 1);
            list[pos] = pv[j] & 0x1FFFFu;
        }
    }
    __syncthreads();
    int scnt = *spillCnt;
    for (int nl0 = w * 16; nl0 < w * 16 + 16; nl0 += 4) {
        int mynode = nl0 + g;
        int n = base + mynode;
        int s0 = st[mynode], e1 = s0 + cnt[mynode];
        float ax = 0.f, ay = 0.f, az = 0.f, aw = 0.f;
        float bx = 0.f, by = 0.f, bz = 0.f, bw = 0.f;
        int i = s0;
        for (; i + 1 < e1; i += 2) {
            unsigned s0v = list[i], s1v = list[i + 1];
            uint2 u0 = *(const uint2*)(y2 + (size_t)s0v * 32 + c * 2);
            uint2 u1 = *(const uint2*)(y2 + (size_t)s1v * 32 + c * 2);
            ax += __uint_as_float(u0.x << 16);
            ay += __uint_as_float(u0.x & 0xffff0000u);
            az += __uint_as_float(u0.y << 16);
            aw += __uint_as_float(u0.y & 0xffff0000u);
            bx += __uint_as_float(u1.x << 16);
            by += __uint_as_float(u1.x & 0xffff0000u);
            bz += __uint_as_float(u1.y << 16);
            bw += __uint_as_float(u1.y & 0xffff0000u);
        }
        if (i < e1) {
            unsigned sv = list[i];
            uint2 u = *(const uint2*)(y2 + (size_t)sv * 32 + c * 2);
            ax += __uint_as_float(u.x << 16);
            ay += __uint_as_float(u.x & 0xffff0000u);
            az += __uint_as_float(u.y << 16);
            aw += __uint_as_float(u.y & 0xffff0000u);
        }
        ax += bx; ay += by; az += bz; aw += bw;
        for (int k = 0; k < scnt; ++k) {
            uint2 e = spill[k];
            if ((int)e.y == n) {
                uint2 u = *(const uint2*)(y2 + (size_t)e.x * 32 + c * 2);
                ax += __uint_as_float(u.x << 16);
                ay += __uint_as_float(u.x & 0xffff0000u);
                az += __uint_as_float(u.y << 16);
                aw += __uint_as_float(u.y & 0xffff0000u);
            }
        }
        if (n < N) {
            float invd = 1.0f / deg[n];
            float4 o4 = {ax * invd + bv.x, ay * invd + bv.y,
                         az * invd + bv.z, aw * invd + bv.w};
            *(float4*)(out + (size_t)n * 64 + c * 4) = o4;
        }
    }
}

// ---- fallback C: atomic scatter + LDS GEMM ------------------------------
__global__ __launch_bounds__(256) void scatter_kernel(
        const float* __restrict__ x, const unsigned* __restrict__ ewords,
        float* __restrict__ agg, int E) {
    __shared__ int sflag;
    int s = detect_stride_block(ewords, E, &sflag);
    int gid = blockIdx.x * blockDim.x + threadIdx.x;
    int e = gid >> 4, q = gid & 15;
    if (e >= E) return;
    int src = (int)ewords[(size_t)e * s];
    int dst = (int)ewords[((size_t)E + e) * s];
    const float4 v = *(const float4*)(x + (size_t)src * D + q * 4);
    float* p = agg + (size_t)dst * D + q * 4;
    unsafeAtomicAdd(p + 0, v.x);
    unsafeAtomicAdd(p + 1, v.y);
    unsafeAtomicAdd(p + 2, v.z);
    unsafeAtomicAdd(p + 3, v.w);
}

__global__ __launch_bounds__(256) void gemm_kernel(
        float* __restrict__ inout, const float* __restrict__ deg,
        const float* __restrict__ W, const float* __restrict__ b, int nNodes) {
    __shared__ float Wt[64 * 65];
    __shared__ float rows[4 * 64];
    int t = threadIdx.x;
    for (int i = t; i < 64 * 64; i += 256) {
        int o = i >> 6, k = i & 63;
        Wt[k * 65 + o] = W[i];
    }
    int base = blockIdx.x * 4;
    int nl = t >> 6, o = t & 63;
    int n = base + nl;
    if (n < nNodes) {
        float invd = 1.0f / deg[n];
        rows[nl * 64 + o] = inout[(size_t)n * 64 + o] * invd;
    }
    __syncthreads();
    if (n >= nNodes) return;
    float acc = b[o];
    #pragma unroll
    for (int k = 0; k < 64; ++k)
        acc += rows[nl * 64 + k] * Wt[k * 65 + o];
    inout[(size_t)n * 64 + o] = acc;
}

extern "C" void kernel_launch(void* const* d_in, const int* in_sizes, int n_in,
                              void* d_out, int out_size, void* d_ws, size_t ws_size,
                              hipStream_t stream) {
    const float*    x      = (const float*)d_in[0];
    const unsigned* ewords = (const unsigned*)d_in[1];
    const float*    deg    = (const float*)d_in[2];
    const float*    W      = (const float*)d_in[3];
    const float*    b      = (const float*)d_in[4];
    float*          out    = (float*)d_out;

    const int E = in_sizes[1] / 2;
    const int N = in_sizes[2];
    const int nb = (N + BNODES - 1) >> BSHIFT;         // 782 for N=100000

    // ws layout: cursor[MAXB] + spillCnt | pairs[nb*CAP] | spill[E] | y2[N*32]
    char* ws = (char*)d_ws;
    size_t curB  = (MAXB + 16) * 4;
    size_t pairB = ((size_t)nb * CAP * 4 + 63) & ~63ull;
    size_t spB   = ((size_t)E * 8 + 63) & ~63ull;
    size_t need  = curB + pairB + spB + (size_t)N * 32 * 4;

    if (ws_size >= need && N < (1 << 17) && nb <= MAXB) {
        int*      cursor   = (int*)ws;
        int*      spillCnt = cursor + MAXB;
        unsigned* pairs    = (unsigned*)(ws + curB);
        uint2*    spill    = (uint2*)(ws + curB + pairB);
        unsigned* y2       = (unsigned*)(ws + curB + pairB + spB);

        int pblocks   = (E + 8191) / 8192;
        int xw64      = (N + 63) / 64;

        // try the cooperative single-kernel path
        void* args[] = {
            (void*)&ewords, (void*)&cursor, (void*)&pairs, (void*)&spill,
            (void*)&spillCnt, (void*)&x, (void*)&W, (void*)&y2,
            (void*)&deg, (void*)&b, (void*)&out,
            (void*)&E, (void*)&N, (void*)&nb, (void*)&pblocks, (void*)&xw64
        };
        hipError_t err = hipLaunchCooperativeKernel(
            (const void*)fused_all, dim3(COOP_GRID), dim3(512), args, 0, stream);

        if (err != hipSuccess) {
            // proven 3-dispatch chain (r10)
            hipMemsetAsync(cursor, 0, curB, stream);
            int xwblocks = (N + 127) / 128;
            partition_xw_kernel<<<pblocks + xwblocks, PXW_THREADS, 0, stream>>>(
                ewords, cursor, pairs, spill, spillCnt, x, W, y2, E, N, nb, pblocks);
            bucket_gather<<<nb, GTHREADS, 0, stream>>>(
                y2, pairs, cursor, spill, spillCnt, deg, b, out, N);
        }
    } else {
        hipMemsetAsync(d_out, 0, (size_t)out_size * sizeof(float), stream);
        long long sthreads = (long long)E * 16;
        int sblocks = (int)((sthreads + 255) / 256);
        scatter_kernel<<<sblocks, 256, 0, stream>>>(x, ewords, out, E);
        gemm_kernel<<<(N + 3) / 4, 256, 0, stream>>>(out, deg, W, b, N);
    }
}

// Round 13
// 142.207 us; speedup vs baseline: 1.8234x; 1.8234x over previous
//
#include <hip/hip_runtime.h>

// SAGEConv-mean: out[n,:] = (sum_{e: dst[e]==n} x[src[e],:]) / deg[n] @ W^T + b
// N=100000, E=1000000, D=64, fp32 in/out (no fp32 MFMA -> VALU GEMM).
//
// Round 13: revert r12's cooperative experiment (fused_all 170us: 512-block grid
// cap -> 2x gather tail, weaker xw tile, grid.sync stragglers). Back to the proven
// r10 3-dispatch chain (140.8us best) + one safe fix: int64 edges loaded as uint2
// (full 64B-line utilization; the old stride-2 word loads wasted half of every
// fetched line).
// Chain: memset(8KB cursors) -> partition_xw -> bucket_gather  (3 dispatches).
// Fallback: atomic scatter + LDS GEMM (ws too small or N >= 2^17 or nb > MAXB).

#define D 64
#define BSHIFT 7                  // 128 nodes per bucket
#define BNODES (1 << BSHIFT)
#define CAP 2048                  // static slots per bucket (mean fill 1280)
#define GTHREADS 512
#define PERTHREAD (CAP / GTHREADS)   // 4
#define PXW_THREADS 512
#define MAXB 2048                 // max buckets supported by partition LDS

// Per-block edge-dtype detect: int64 little-endian => odd 32-bit words are zero
// high-halves. 64 samples -> P(false int32 hit) ~ (1/N)^64 ~ 0.
__device__ inline int detect_stride_block(const unsigned* __restrict__ words,
                                          int E, int* sflag) {
    int t = threadIdx.x;
    if (t < 64) {
        unsigned v = (t < E) ? words[2 * t + 1] : 0u;
        int any = __any(v != 0u);
        if (t == 0) *sflag = any ? 1 : 2;   // word stride: 1=int32, 2=int64
    }
    __syncthreads();
    return *sflag;
}

// dense edge load: int64 path fetches both halves (full line use), drops high
__device__ inline void load_edge(const unsigned* __restrict__ ewords,
                                 int s, int E, int e,
                                 unsigned& src, unsigned& dst) {
    if (s == 2) {
        uint2 sv = ((const uint2*)ewords)[e];
        uint2 dv = ((const uint2*)ewords)[(size_t)E + e];
        src = sv.x; dst = dv.x;
    } else {
        src = ewords[e];
        dst = ewords[(size_t)E + e];
    }
}

__device__ inline unsigned pack_bf16(float a, float b) {   // two fp32 -> bf16x2, RNE
    unsigned ua = __float_as_uint(a), ub = __float_as_uint(b);
    ua += 0x7fffu + ((ua >> 16) & 1u);
    ub += 0x7fffu + ((ub >> 16) & 1u);
    return (ua >> 16) | (ub & 0xffff0000u);
}

// ---- fused partition (blocks [0,pblocks)) + xw GEMM (rest), 512 thr -----
__global__ __launch_bounds__(PXW_THREADS, 4) void partition_xw_kernel(
        const unsigned* __restrict__ ewords, int* __restrict__ cursor,
        unsigned* __restrict__ pairs, uint2* __restrict__ spill,
        int* __restrict__ spillCnt,
        const float* __restrict__ x, const float* __restrict__ W,
        unsigned* __restrict__ y2, int E, int N, int nb, int pblocks) {
    __shared__ __align__(16) char smem[52240];   // xw 52224B | part 16388B
    int t = threadIdx.x;

    if ((int)blockIdx.x < pblocks) {
        // ---------------- partition: 8192 edges, one pass ----------------
        int* lhist = (int*)smem;
        int* lbase = lhist + MAXB;
        int* sflag = lbase + MAXB;
        int s = detect_stride_block(ewords, E, sflag);
        int base = blockIdx.x * 8192;
        for (int i = t; i < nb; i += PXW_THREADS) lhist[i] = 0;
        __syncthreads();
        unsigned pv[16]; int bk[16];
        #pragma unroll
        for (int k = 0; k < 16; ++k) {
            int e = base + k * PXW_THREADS + t;
            bk[k] = -1;
            if (e < E) {
                unsigned src, dst;
                load_edge(ewords, s, E, e, src, dst);
                bk[k] = (int)(dst >> BSHIFT);
                pv[k] = src | ((dst & (BNODES - 1)) << 17);
                atomicAdd(&lhist[bk[k]], 1);
            }
        }
        __syncthreads();
        for (int hb = t; hb < nb; hb += PXW_THREADS) {
            int cc = lhist[hb];
            if (cc) lbase[hb] = atomicAdd(&cursor[hb], cc);
            lhist[hb] = 0;                    // reuse as running cursor
        }
        __syncthreads();
        #pragma unroll
        for (int k = 0; k < 16; ++k) {
            if (bk[k] >= 0) {
                int lpos = lbase[bk[k]] + atomicAdd(&lhist[bk[k]], 1);
                if (lpos < CAP) {
                    pairs[(size_t)bk[k] * CAP + lpos] = pv[k];
                } else {                      // overflow (never for this input)
                    int si = atomicAdd(spillCnt, 1);
                    unsigned dst = ((unsigned)bk[k] << BSHIFT) | (pv[k] >> 17);
                    spill[si] = make_uint2(pv[k] & 0x1FFFFu, dst);
                }
            }
        }
    } else {
        // ---------------- xw: 128-node tile, y = x @ W^T -> bf16 ---------
        float* Wt = (float*)smem;                 // Wt[k*68+o], 17408B
        float* xs = Wt + 64 * 68;                 // xs[nl*68+k], 34816B
        for (int i = t; i < 64 * 64; i += PXW_THREADS) {
            int o = i >> 6, k = i & 63;
            Wt[k * 68 + o] = W[i];
        }
        int base = ((int)blockIdx.x - pblocks) * 128;
        int row = t >> 4, c4 = (t & 15) * 4;      // row 0..31
        #pragma unroll
        for (int r = 0; r < 4; ++r) {
            int nl = row + r * 32;
            int n = base + nl;
            float4 v = {0.f, 0.f, 0.f, 0.f};
            if (n < N) v = *(const float4*)(x + (size_t)n * 64 + c4);
            *(float4*)&xs[nl * 68 + c4] = v;
        }
        __syncthreads();
        int o4 = (t & 15) * 4, nl4 = (t >> 4) * 4;   // nl4 0..124
        float acc[4][4];
        #pragma unroll
        for (int i = 0; i < 4; ++i)
            #pragma unroll
            for (int j = 0; j < 4; ++j) acc[i][j] = 0.f;
        #pragma unroll 2
        for (int k0 = 0; k0 < 64; k0 += 4) {
            float a[4][4], wv[4][4];
            #pragma unroll
            for (int i = 0; i < 4; ++i)
                *(float4*)a[i] = *(const float4*)&xs[(nl4 + i) * 68 + k0];
            #pragma unroll
            for (int dk = 0; dk < 4; ++dk)
                *(float4*)wv[dk] = *(const float4*)&Wt[(k0 + dk) * 68 + o4];
            #pragma unroll
            for (int i = 0; i < 4; ++i)
                #pragma unroll
                for (int j = 0; j < 4; ++j)
                    acc[i][j] += a[i][0] * wv[0][j] + a[i][1] * wv[1][j]
                               + a[i][2] * wv[2][j] + a[i][3] * wv[3][j];
        }
        int n0 = base + nl4;
        #pragma unroll
        for (int i = 0; i < 4; ++i) {
            if (n0 + i < N) {
                uint2 p;
                p.x = pack_bf16(acc[i][0], acc[i][1]);
                p.y = pack_bf16(acc[i][2], acc[i][3]);
                *(uint2*)(y2 + (size_t)(n0 + i) * 32 + (o4 >> 1)) = p;
            }
        }
    }
}

// ---- bucket gather: counting-sort + dual-accumulator register gather ----
__global__ __launch_bounds__(GTHREADS) void bucket_gather(
        const unsigned* __restrict__ y2, const unsigned* __restrict__ pairs,
        const int* __restrict__ cursor, const uint2* __restrict__ spill,
        const int* __restrict__ spillCnt,
        const float* __restrict__ deg, const float* __restrict__ b,
        float* __restrict__ out, int N) {
    __shared__ unsigned list[CAP];           // sorted srcs, 8 KB
    __shared__ int cnt[BNODES], st[BNODES], sc[BNODES];
    int t = threadIdx.x;
    int bkt = blockIdx.x, base = bkt << BSHIFT;
    int total = cursor[bkt];
    int cn = total < CAP ? total : CAP;      // slots [0,cn) valid; rest spilled
    int lane = t & 63, w = t >> 6;           // 8 waves
    int g = lane >> 4, c = lane & 15;        // node sub-index / column quad
    float4 bv = ((const float4*)b)[c];

    if (t < BNODES) cnt[t] = 0;
    __syncthreads();
    unsigned pv[PERTHREAD];
    #pragma unroll
    for (int j = 0; j < PERTHREAD; ++j) {             // one coalesced pass
        int i = t + j * GTHREADS;
        pv[j] = (i < cn) ? pairs[(size_t)bkt * CAP + i] : 0xFFFFFFFFu;
        if (i < cn) atomicAdd(&cnt[pv[j] >> 17], 1);  // hist from registers
    }
    __syncthreads();
    if (t < BNODES) sc[t] = cnt[t];
    __syncthreads();
    for (int off = 1; off < BNODES; off <<= 1) {      // inclusive scan
        int v = (t < BNODES && t >= off) ? sc[t - off] : 0;
        __syncthreads();
        if (t < BNODES) sc[t] += v;
        __syncthreads();
    }
    if (t < BNODES) { st[t] = sc[t] - cnt[t]; sc[t] = sc[t] - cnt[t]; }
    __syncthreads();
    #pragma unroll
    for (int j = 0; j < PERTHREAD; ++j) {             // scatter from registers
        if (pv[j] != 0xFFFFFFFFu) {
            int pos = atomicAdd(&sc[pv[j] >> 17], 1);
            list[pos] = pv[j] & 0x1FFFFu;             // src only
        }
    }
    __syncthreads();

    int scnt = *spillCnt;                             // 0 in practice

    // gather: wave w owns nodes [w*16, w*16+16); 4 nodes per step via g
    for (int nl0 = w * 16; nl0 < w * 16 + 16; nl0 += 4) {
        int mynode = nl0 + g;
        int n = base + mynode;
        int s0 = st[mynode], e1 = s0 + cnt[mynode];
        float ax = 0.f, ay = 0.f, az = 0.f, aw = 0.f;   // even edges
        float bx = 0.f, by = 0.f, bz = 0.f, bw = 0.f;   // odd edges
        int i = s0;
        for (; i + 1 < e1; i += 2) {                  // 2 loads in flight
            unsigned s0v = list[i], s1v = list[i + 1];
            uint2 u0 = *(const uint2*)(y2 + (size_t)s0v * 32 + c * 2);
            uint2 u1 = *(const uint2*)(y2 + (size_t)s1v * 32 + c * 2);
            ax += __uint_as_float(u0.x << 16);
            ay += __uint_as_float(u0.x & 0xffff0000u);
            az += __uint_as_float(u0.y << 16);
            aw += __uint_as_float(u0.y & 0xffff0000u);
            bx += __uint_as_float(u1.x << 16);
            by += __uint_as_float(u1.x & 0xffff0000u);
            bz += __uint_as_float(u1.y << 16);
            bw += __uint_as_float(u1.y & 0xffff0000u);
        }
        if (i < e1) {
            unsigned sv = list[i];
            uint2 u = *(const uint2*)(y2 + (size_t)sv * 32 + c * 2);
            ax += __uint_as_float(u.x << 16);
            ay += __uint_as_float(u.x & 0xffff0000u);
            az += __uint_as_float(u.y << 16);
            aw += __uint_as_float(u.y & 0xffff0000u);
        }
        ax += bx; ay += by; az += bz; aw += bw;
        for (int k = 0; k < scnt; ++k) {              // overflow path (empty)
            uint2 e = spill[k];
            if ((int)e.y == n) {
                uint2 u = *(const uint2*)(y2 + (size_t)e.x * 32 + c * 2);
                ax += __uint_as_float(u.x << 16);
                ay += __uint_as_float(u.x & 0xffff0000u);
                az += __uint_as_float(u.y << 16);
                aw += __uint_as_float(u.y & 0xffff0000u);
            }
        }
        if (n < N) {
            float invd = 1.0f / deg[n];
            float4 o4 = {ax * invd + bv.x, ay * invd + bv.y,
                         az * invd + bv.z, aw * invd + bv.w};
            *(float4*)(out + (size_t)n * 64 + c * 4) = o4;
        }
    }
}

// ---- fallback: atomic scatter + LDS GEMM --------------------------------
__global__ __launch_bounds__(256) void scatter_kernel(
        const float* __restrict__ x, const unsigned* __restrict__ ewords,
        float* __restrict__ agg, int E) {
    __shared__ int sflag;
    int s = detect_stride_block(ewords, E, &sflag);
    int gid = blockIdx.x * blockDim.x + threadIdx.x;
    int e = gid >> 4, q = gid & 15;
    if (e >= E) return;
    unsigned src, dst;
    load_edge(ewords, s, E, e, src, dst);
    const float4 v = *(const float4*)(x + (size_t)src * D + q * 4);
    float* p = agg + (size_t)dst * D + q * 4;
    unsafeAtomicAdd(p + 0, v.x);
    unsafeAtomicAdd(p + 1, v.y);
    unsafeAtomicAdd(p + 2, v.z);
    unsafeAtomicAdd(p + 3, v.w);
}

__global__ __launch_bounds__(256) void gemm_kernel(
        float* __restrict__ inout, const float* __restrict__ deg,
        const float* __restrict__ W, const float* __restrict__ b, int nNodes) {
    __shared__ float Wt[64 * 65];
    __shared__ float rows[4 * 64];
    int t = threadIdx.x;
    for (int i = t; i < 64 * 64; i += 256) {
        int o = i >> 6, k = i & 63;
        Wt[k * 65 + o] = W[i];
    }
    int base = blockIdx.x * 4;
    int nl = t >> 6, o = t & 63;
    int n = base + nl;
    if (n < nNodes) {
        float invd = 1.0f / deg[n];
        rows[nl * 64 + o] = inout[(size_t)n * 64 + o] * invd;
    }
    __syncthreads();
    if (n >= nNodes) return;
    float acc = b[o];
    #pragma unroll
    for (int k = 0; k < 64; ++k)
        acc += rows[nl * 64 + k] * Wt[k * 65 + o];
    inout[(size_t)n * 64 + o] = acc;
}

extern "C" void kernel_launch(void* const* d_in, const int* in_sizes, int n_in,
                              void* d_out, int out_size, void* d_ws, size_t ws_size,
                              hipStream_t stream) {
    const float*    x      = (const float*)d_in[0];
    const unsigned* ewords = (const unsigned*)d_in[1];
    const float*    deg    = (const float*)d_in[2];
    const float*    W      = (const float*)d_in[3];
    const float*    b      = (const float*)d_in[4];
    float*          out    = (float*)d_out;

    const int E = in_sizes[1] / 2;
    const int N = in_sizes[2];
    const int nb = (N + BNODES - 1) >> BSHIFT;         // 782 for N=100000

    // ws layout: cursor[MAXB] + spillCnt | pairs[nb*CAP] | spill[E] | y2[N*32]
    char* ws = (char*)d_ws;
    size_t curB  = (MAXB + 16) * 4;
    size_t pairB = ((size_t)nb * CAP * 4 + 63) & ~63ull;
    size_t spB   = ((size_t)E * 8 + 63) & ~63ull;
    size_t need  = curB + pairB + spB + (size_t)N * 32 * 4;

    if (ws_size >= need && N < (1 << 17) && nb <= MAXB) {
        int*      cursor   = (int*)ws;
        int*      spillCnt = cursor + MAXB;
        unsigned* pairs    = (unsigned*)(ws + curB);
        uint2*    spill    = (uint2*)(ws + curB + pairB);
        unsigned* y2       = (unsigned*)(ws + curB + pairB + spB);

        hipMemsetAsync(cursor, 0, curB, stream);       // 8KB: cursors + spillCnt

        int pblocks  = (E + 8191) / 8192;
        int xwblocks = (N + 127) / 128;
        partition_xw_kernel<<<pblocks + xwblocks, PXW_THREADS, 0, stream>>>(
            ewords, cursor, pairs, spill, spillCnt, x, W, y2, E, N, nb, pblocks);

        bucket_gather<<<nb, GTHREADS, 0, stream>>>(
            y2, pairs, cursor, spill, spillCnt, deg, b, out, N);
    } else {
        hipMemsetAsync(d_out, 0, (size_t)out_size * sizeof(float), stream);
        long long sthreads = (long long)E * 16;
        int sblocks = (int)((sthreads + 255) / 256);
        scatter_kernel<<<sblocks, 256, 0, stream>>>(x, ewords, out, E);
        gemm_kernel<<<(N + 3) / 4, 256, 0, stream>>>(out, deg, W, b, N);
    }
}